// Round 21
// baseline (1406.831 us; speedup 1.0000x reference)
//
#include <hip/hip_runtime.h>
#include <hip/hip_bf16.h>
#include <cstdint>

typedef __attribute__((ext_vector_type(8))) short short8;
typedef __attribute__((ext_vector_type(4))) float f32x4;
typedef __attribute__((ext_vector_type(4))) short short4v;

#define WM 262144L   // 512*512

__device__ __forceinline__ float b2f(short s) {
    unsigned u = ((unsigned)(unsigned short)s) << 16;
    return __builtin_bit_cast(float, u);
}
__device__ __forceinline__ short f2b(float f) {
    unsigned u = __builtin_bit_cast(unsigned, f);
    u += 0x7fff + ((u >> 16) & 1);   // RNE
    return (short)(u >> 16);
}

// tanh-form GELU, 8-VALU: gelu = x - x/(1+exp2(x*(c1 + c2*x^2)))
__device__ __forceinline__ float gelu_t(float x) {
    const float c1 = 2.302184829f;
    const float c2 = 0.102947246f;
    float x2 = x * x;
    float t  = __builtin_fmaf(c2, x2, c1);
    float e  = __builtin_amdgcn_exp2f(x * t);
    return x - __fdividef(x, e + 1.0f);
}

__device__ __forceinline__ void async16(const void* g, void* l) {
    __builtin_amdgcn_global_load_lds(
        (const __attribute__((address_space(1))) unsigned int*)g,
        (__attribute__((address_space(3))) unsigned int*)l, 16, 0, 0);
}

#define VMW(N) asm volatile("s_waitcnt vmcnt(" #N ")" ::: "memory")

// =====================================================================
// Mega v4: block = 64 x-rows × one view k (blockIdx.z 0..11).
//   k==0: 3 layers (fold F, E2, E3);  k>=1: 5 layers (L1,L2,F,E2,E3)
// Ash[64][512] bf16 swizzled (chunk ^ row&15), 64 KB — activations
// never leave LDS. W streamed global->LDS, DOUBLE-buffered [512][32]
// (2x32 KB), r19 counted-vmcnt discipline: stage(s+1) in flight across
// raw barriers, vmcnt(4), never drained mid-loop. 128 KB LDS, 8 waves.
// Wave w owns output cols [w*64, w*64+64): acc[4][4].
// Writes pre-LN output tile to T (ln_loss consumes as before).
// =====================================================================
__global__ __launch_bounds__(512)
void mega(const short* __restrict__ xb, const short* __restrict__ wt,
          const short* __restrict__ Mt,
          const float* __restrict__ tb1, const float* __restrict__ tb2,
          const float* __restrict__ bB,
          const float* __restrict__ eb2v, const float* __restrict__ eb3v,
          short* __restrict__ T, int CH) {
    __shared__ alignas(16) short Ash[64 * 512];     // 65536 B
    __shared__ alignas(16) short Wb[2][512 * 32];   // 2 x 32768 B

    const int tid = threadIdx.x, lane = tid & 63, w = tid >> 6;
    const int lr = lane & 15, hi = lane >> 4;
    const int kview = blockIdx.z;
    const long row0 = (long)blockIdx.x * 64;
    const int L  = (kview == 0) ? 3 : 5;
    const int NS = L * 16;

    // ---- x tile -> Ash (swizzled; coalesced 16B/lane) ----
#pragma unroll
    for (int it = 0; it < 8; ++it) {
        const int idx = it * 512 + tid;
        const int r = idx >> 6, cch = idx & 63;
        short8 v = *(const short8*)&xb[(row0 + r) * 512 + cch * 8];
        *(short8*)&Ash[r * 512 + ((cch ^ (r & 15)) << 3)] = v;
    }
    asm volatile("s_waitcnt lgkmcnt(0)" ::: "memory");   // publish at first barrier

    auto wmat = [&](int l) -> const short* {
        if (kview == 0) return (l == 0) ? Mt : (l == 1) ? wt + 34 * WM : wt + 35 * WM;
        return (l == 0) ? wt + (long)(kview - 1) * WM
             : (l == 1) ? wt + (long)(11 + kview - 1) * WM
             : (l == 2) ? Mt + (long)kview * WM
             : (l == 3) ? wt + 34 * WM : wt + 35 * WM;
    };

    // stage W k32-slice [512 n-rows][32 k] into Wb[q]; rows 64 B,
    // src chunk pre-swizzled key (row>>1)&3, LDS dest lane-linear.
    auto stageW = [&](int q, int s) {
        const short* Wsrc = wmat(s >> 4);
        const int kc = (s & 15) * 32;
        short* dst = &Wb[q][0];
#pragma unroll
        for (int i = 0; i < 4; ++i) {
            const int R = w * 64 + i * 16;            // wave-uniform base
            const int row = R + (lane >> 2);
            const int gc = (lane & 3) ^ ((row >> 1) & 3);
            async16(Wsrc + (long)row * 512 + kc + gc * 8, dst + R * 32);
        }
    };

    f32x4 acc[4][4] = {};
    stageW(0, 0);
    int buf = 0;
    for (int s = 0; s < NS; ++s) {
        if (s + 1 < NS) { stageW(buf ^ 1, s + 1); VMW(4); }
        else            { VMW(0); }
        __builtin_amdgcn_sched_barrier(0);
        __builtin_amdgcn_s_barrier();      // W(s) + prev Ash writes visible
        __builtin_amdgcn_sched_barrier(0);

        const short* Wc = &Wb[buf][0];
        short8 a[4], b[4];
        const int ach = (s & 15) * 4 + hi;            // 16B-chunk in Ash row
#pragma unroll
        for (int n = 0; n < 4; ++n) {
            const int nr = w * 64 + n * 16 + lr;
            b[n] = *(const short8*)&Wc[nr * 32 + ((hi ^ ((nr >> 1) & 3)) << 3)];
        }
#pragma unroll
        for (int m = 0; m < 4; ++m) {
            const int row = m * 16 + lr;
            a[m] = *(const short8*)&Ash[row * 512 + ((ach ^ (row & 15)) << 3)];
        }
        __builtin_amdgcn_s_setprio(1);
#pragma unroll
        for (int m = 0; m < 4; ++m)
#pragma unroll
            for (int n = 0; n < 4; ++n)
                acc[m][n] = __builtin_amdgcn_mfma_f32_16x16x32_bf16(
                    a[m], b[n], acc[m][n], 0, 0, 0);
        __builtin_amdgcn_s_setprio(0);

        __builtin_amdgcn_sched_barrier(0);
        __builtin_amdgcn_s_barrier();      // reads of Wb[buf]/Ash done -> safe overwrite

        if ((s & 15) == 15) {
            // ---- layer epilogue: bias (+GELU), bf16, write back to Ash ----
            const int l = s >> 4;
            const float* bp; bool g;
            if (kview == 0) {
                bp = (l == 0) ? bB : (l == 1) ? eb2v : eb3v; g = (l < 2);
            } else {
                bp = (l == 0) ? tb1 + (long)(kview - 1) * 512
                   : (l == 1) ? tb2 + (long)(kview - 1) * 512
                   : (l == 2) ? bB + (long)kview * 512
                   : (l == 3) ? eb2v : eb3v;
                g = (l < 4);
            }
#pragma unroll
            for (int n = 0; n < 4; ++n) {
                const int col = w * 64 + n * 16 + lr;
                const float bv = bp[col];
#pragma unroll
                for (int m = 0; m < 4; ++m) {
#pragma unroll
                    for (int i = 0; i < 4; ++i) {
                        const int row = m * 16 + hi * 4 + i;
                        float v = acc[m][n][i] + bv;
                        if (g) v = gelu_t(v);
                        Ash[row * 512 + (((col >> 3) ^ (row & 15)) << 3) + (col & 7)] = f2b(v);
                    }
                    acc[m][n] = (f32x4){0.f, 0.f, 0.f, 0.f};
                }
            }
            asm volatile("s_waitcnt lgkmcnt(0)" ::: "memory");  // drain before next barrier
        }
        buf ^= 1;
    }

    __builtin_amdgcn_s_barrier();          // final epilogue visible to all waves

    // ---- write pre-LN output tile to T (coalesced) ----
#pragma unroll
    for (int it = 0; it < 8; ++it) {
        const int idx = it * 512 + tid;
        const int r = idx >> 6, cch = idx & 63;
        short8 v = *(const short8*)&Ash[r * 512 + ((cch ^ (r & 15)) << 3)];
        *(short8*)&T[((long)kview * CH + row0 + r) * 512 + cch * 8] = v;
    }
}

// ===== r20 split GEMM (kept for Mt prep only) =====
template<bool GELU>
__global__ __launch_bounds__(512)
void gemm_bt(const short* __restrict__ A, long sA,
             const short* __restrict__ Bt, long sB,
             const float* __restrict__ bias, long sBias,
             short* __restrict__ C, long sC) {
    const int z = blockIdx.z;
    A    += (long)z * sA;
    Bt   += (long)z * sB;
    bias += (long)z * sBias;
    C    += (long)z * sC;

    const int nwg = (int)gridDim.x;
    const int bx  = (int)blockIdx.x;
    int flat = bx;
    if ((nwg & 7) == 0) { const int q = nwg >> 3; flat = (bx & 7) * q + (bx >> 3); }
    const long arow0 = (long)(flat >> 1) * 256;
    const long brow0 = (long)(flat & 1) * 256;

    __shared__ alignas(16) short smem[2 * 32768];

    const int tid  = threadIdx.x;
    const int lane = tid & 63;
    const int w    = tid >> 6;
    const int wrow = w >> 2, wcol = w & 3;
    const int lr = lane & 15, hi = lane >> 4;

    f32x4 acc[8][4] = {};

    auto stageH = [&](int st, int sks, int sB_) {
        short* reg = smem + (st & 1) * 32768 + (sB_ ? 16384 : 0) + sks * 8192;
        const short* srcb = sB_ ? Bt : A;
        const long r0g = sB_ ? brow0 : arow0;
        const int kc = st * 64 + sks * 32;
#pragma unroll
        for (int jj = 0; jj < 2; ++jj) {
            const int R = w * 32 + jj * 16;
            const int row = R + (lane >> 2);
            const int gc = (lane & 3) ^ ((row >> 1) & 3);
            async16(srcb + (r0g + row) * 512 + kc + gc * 8, reg + R * 32);
        }
    };

    stageH(0, 0, 0); stageH(0, 0, 1);
    stageH(0, 1, 0); stageH(0, 1, 1);
    stageH(1, 0, 0); stageH(1, 0, 1);

    short8 b[4];
#pragma unroll
    for (int i = 0; i < 4; ++i) {
#pragma unroll
        for (int p = 0; p < 8; ++p) {
            const int tau = 2 * i + (p >> 2);
            const int ks  = (p >> 1) & 1;
            const int mh  = p & 1;
            const short* Ar = smem + (tau & 1) * 32768 + ks * 8192;
            const short* Br = Ar + 16384;

            if (mh == 0) {
                if (i < 3)       { VMW(8); }
                else if (p == 0) { VMW(8); }
                else if (p == 2) { VMW(8); }
                else if (p == 4) { VMW(4); }
                else             { VMW(0); }
                __builtin_amdgcn_s_barrier();
                __builtin_amdgcn_sched_barrier(0);
#pragma unroll
                for (int n = 0; n < 4; ++n) {
                    const int row = wcol * 64 + n * 16 + lr;
                    b[n] = *(const short8*)&Br[row * 32 + ((hi ^ ((row >> 1) & 3)) << 3)];
                }
            }

            short8 a[4];
#pragma unroll
            for (int j = 0; j < 4; ++j) {
                const int row = wrow * 128 + (mh * 4 + j) * 16 + lr;
                a[j] = *(const short8*)&Ar[row * 32 + ((hi ^ ((row >> 1) & 3)) << 3)];
            }
            {
                const int st  = (p < 2) ? 2 * i + 1 : (p < 6) ? 2 * i + 2 : 2 * i + 3;
                const int sks = (p < 2) ? 1 : (p < 4) ? 0 : (p < 6) ? 1 : 0;
                const int sB_ = p & 1;
                if (st < 8) stageH(st, sks, sB_);
            }
            __builtin_amdgcn_s_setprio(1);
#pragma unroll
            for (int j = 0; j < 4; ++j)
#pragma unroll
                for (int n = 0; n < 4; ++n)
                    acc[mh * 4 + j][n] = __builtin_amdgcn_mfma_f32_16x16x32_bf16(
                        a[j], b[n], acc[mh * 4 + j][n], 0, 0, 0);
            __builtin_amdgcn_s_setprio(0);

            if (mh == 1) {
                __builtin_amdgcn_sched_barrier(0);
                __builtin_amdgcn_s_barrier();
            }
        }
    }

    short* E = smem + w * (32 * 72);
    const int cl = lr, rl = hi * 4;
#pragma unroll
    for (int h = 0; h < 4; ++h) {
#pragma unroll
        for (int n = 0; n < 4; ++n) {
            const int col = (int)brow0 + wcol * 64 + n * 16 + cl;
            const float bs = bias[col];
            const int ecol = n * 16 + cl;
#pragma unroll
            for (int ml = 0; ml < 2; ++ml) {
                const int m = h * 2 + ml;
                float g0 = acc[m][n][0] + bs, g1 = acc[m][n][1] + bs;
                float g2 = acc[m][n][2] + bs, g3 = acc[m][n][3] + bs;
                if (GELU) { g0 = gelu_t(g0); g1 = gelu_t(g1); g2 = gelu_t(g2); g3 = gelu_t(g3); }
                unsigned p01, p23;
                asm("v_cvt_pk_bf16_f32 %0, %1, %2" : "=v"(p01) : "v"(g0), "v"(g1));
                asm("v_cvt_pk_bf16_f32 %0, %1, %2" : "=v"(p23) : "v"(g2), "v"(g3));
                const int r0 = ml * 16 + rl;
                E[(r0 + 0) * 72 + ecol] = (short)(p01 & 0xffff);
                E[(r0 + 1) * 72 + ecol] = (short)(p01 >> 16);
                E[(r0 + 2) * 72 + ecol] = (short)(p23 & 0xffff);
                E[(r0 + 3) * 72 + ecol] = (short)(p23 >> 16);
            }
        }
#pragma unroll
        for (int chunk = 0; chunk < 4; ++chunk) {
            const int rloc = chunk * 8 + (lane >> 3);
            const int c0   = (lane & 7) * 8;
            short8 v = *(const short8*)&E[rloc * 72 + c0];
            *(short8*)&C[(arow0 + wrow * 128 + h * 32 + rloc) * 512
                         + brow0 + wcol * 64 + c0] = v;
        }
    }
}

// ---- transpose+convert ----
__global__ __launch_bounds__(256)
void transpose_conv(const float* __restrict__ src, short* __restrict__ dst) {
    __shared__ float t[32][33];
    const long moff = (long)blockIdx.z * 512 * 512;
    const float* s = src + moff;
    short* d = dst + moff;
    const int tx = threadIdx.x & 31, ty = threadIdx.x >> 5;
    const int bi = blockIdx.x, bj = blockIdx.y;
#pragma unroll
    for (int j = 0; j < 4; ++j)
        t[ty + j * 8][tx] = s[(long)(bi * 32 + ty + j * 8) * 512 + bj * 32 + tx];
    __syncthreads();
#pragma unroll
    for (int j = 0; j < 4; ++j)
        d[(long)(bj * 32 + ty + j * 8) * 512 + bi * 32 + tx] = f2b(t[tx][ty + j * 8]);
}

// ---- f32 -> bf16 elementwise ----
__global__ __launch_bounds__(256)
void conv_f32_bf16(const float* __restrict__ src, short* __restrict__ dst, long n) {
    long i = ((long)blockIdx.x * 256 + threadIdx.x) * 4;
    if (i >= n) return;
    float4 f = *(const float4*)&src[i];
    short4v o;
    o[0] = f2b(f.x); o[1] = f2b(f.y); o[2] = f2b(f.z); o[3] = f2b(f.w);
    *(short4v*)&dst[i] = o;
}

// ---- bias fold ----
__global__ __launch_bounds__(256)
void bias_fold(const float* __restrict__ tb3, const short* __restrict__ wtE1,
               const float* __restrict__ eb1, float* __restrict__ bB) {
    const int wid = threadIdx.x >> 6, lane = threadIdx.x & 63;
    const int idx = blockIdx.x * 4 + wid;
    const int k = idx >> 9, n = idx & 511;
    short8 wv = *(const short8*)&wtE1[(long)n * 512 + lane * 8];
    const float* tb = tb3 + (long)k * 512 + lane * 8;
    float s = 0.f;
#pragma unroll
    for (int j = 0; j < 8; ++j) s += b2f(wv[j]) * tb[j];
#pragma unroll
    for (int o = 1; o < 64; o <<= 1) s += __shfl_xor(s, o, 64);
    if (lane == 0) bB[(long)(k + 1) * 512 + n] = s + eb1[n];
}

// ---- fused LN + L2-normalize + MFMA Gram + logsumexp loss ----
__global__ __launch_bounds__(256)
void ln_loss(const short* __restrict__ H, const float* __restrict__ g,
             const float* __restrict__ bta, float* __restrict__ out, int CH) {
    __shared__ alignas(16) short Z[4][16 * 520];
    const int wid = threadIdx.x >> 6, lane = threadIdx.x & 63;
    const long b = (long)blockIdx.x * 4 + wid;
    short* Zw = &Z[wid][0];

#pragma unroll
    for (int r = 12; r < 16; ++r)
        *(short8*)&Zw[r * 520 + lane * 8] = (short8){0, 0, 0, 0, 0, 0, 0, 0};

    for (int s = 0; s < 12; ++s) {
        short8 t = *(const short8*)&H[((long)s * CH + b) * 512 + lane * 8];
        float v[8];
        float sum = 0.f, ss = 0.f;
#pragma unroll
        for (int j = 0; j < 8; ++j) { v[j] = b2f(t[j]); sum += v[j]; ss += v[j] * v[j]; }
#pragma unroll
        for (int o = 1; o < 64; o <<= 1) { sum += __shfl_xor(sum, o, 64); ss += __shfl_xor(ss, o, 64); }
        const float mu = sum * (1.f / 512.f);
        const float rs = rsqrtf(ss * (1.f / 512.f) - mu * mu + 1e-5f);
        float y[8]; float nsq = 0.f;
#pragma unroll
        for (int j = 0; j < 8; ++j) {
            const int col = lane * 8 + j;
            y[j] = (v[j] - mu) * rs * g[col] + bta[col];
            nsq += y[j] * y[j];
        }
#pragma unroll
        for (int o = 1; o < 64; o <<= 1) nsq += __shfl_xor(nsq, o, 64);
        const float inv = 1.f / fmaxf(sqrtf(nsq), 1e-8f);
        short8 o8;
#pragma unroll
        for (int j = 0; j < 8; ++j) o8[j] = f2b(y[j] * inv);
        *(short8*)&Zw[s * 520 + lane * 8] = o8;
    }

    f32x4 acc = {0.f, 0.f, 0.f, 0.f};
    const int lr = lane & 15, hi = lane >> 4;
#pragma unroll
    for (int st = 0; st < 16; ++st) {
        short8 a = *(const short8*)&Zw[lr * 520 + st * 32 + hi * 8];
        acc = __builtin_amdgcn_mfma_f32_16x16x32_bf16(a, a, acc, 0, 0, 0);
    }
    const int col = lr;
    float lmax = -3.0e38f;
    bool valid[4];
#pragma unroll
    for (int i = 0; i < 4; ++i) {
        const int row = hi * 4 + i;
        valid[i] = (row < 12) && (row != col);
        if (valid[i]) lmax = fmaxf(lmax, acc[i]);
    }
    lmax = fmaxf(lmax, __shfl_xor(lmax, 16, 64));
    lmax = fmaxf(lmax, __shfl_xor(lmax, 32, 64));
    float esum = 0.f;
#pragma unroll
    for (int i = 0; i < 4; ++i)
        if (valid[i]) esum += __builtin_amdgcn_exp2f((acc[i] - lmax) * 1.44269504f);
    esum += __shfl_xor(esum, 16, 64);
    esum += __shfl_xor(esum, 32, 64);
    float contrib = 0.f;
    if (hi == 0 && col >= 1 && col <= 11) {
        const float logden = lmax + __builtin_amdgcn_logf(esum) * 0.6931471806f;
        contrib = acc[0] - logden;
    }
#pragma unroll
    for (int o = 1; o < 16; o <<= 1) contrib += __shfl_xor(contrib, o, 64);
    if (lane == 0) out[b] = -contrib;
}

// ---------------- host ----------------
extern "C" void kernel_launch(void* const* d_in, const int* in_sizes, int n_in,
                              void* d_out, int out_size, void* d_ws, size_t ws_size,
                              hipStream_t stream) {
    const float* x    = (const float*)d_in[0];
    const float* tW1  = (const float*)d_in[1];
    const float* tb1  = (const float*)d_in[2];
    const float* tW2  = (const float*)d_in[3];
    const float* tb2  = (const float*)d_in[4];
    const float* tW3  = (const float*)d_in[5];
    const float* tb3  = (const float*)d_in[6];
    const float* eW1  = (const float*)d_in[7];
    const float* eb1  = (const float*)d_in[8];
    const float* eW2  = (const float*)d_in[9];
    const float* eb2  = (const float*)d_in[10];
    const float* eW3  = (const float*)d_in[11];
    const float* eb3  = (const float*)d_in[12];
    const float* ln_g = (const float*)d_in[13];
    const float* ln_b = (const float*)d_in[14];

    const int  B = in_sizes[0] / 512;   // 16384

    // ---- adaptive chunking: weights(48 WM bf16) + biases + xb + 12 T-slabs ----
    int  c  = 1;
    long CH = B;
    for (;;) {
        CH = (long)B / c;
        size_t need = (size_t)48 * WM * 2 + (512 + 12 * 512) * 4
                    + (size_t)13 * CH * 512 * 2 + 8192;
        if (need <= ws_size || CH <= 256) break;
        c <<= 1;
    }

    short* wt   = (short*)d_ws;             // 0..10 tW1^T, 11..21 tW2^T, 22..32 tW3(orig bf16), 33..35 eW^T
    short* Mt   = wt + 36L * WM;            // slot0 = eW1^T, 1..11 = (tW3_k·eW1)^T
    float* zero512 = (float*)(Mt + 12L * WM);
    float* bB   = zero512 + 512;            // 12x512 folded biases (row0 = eb1)
    short* xb   = (short*)(bB + 12 * 512);  // [CH,512] bf16 x chunk
    short* T    = xb + CH * 512;            // [12,CH,512] bf16 pre-LN outputs

    // --- weight prep (once per launch) ---
    {
        dim3 tgK(16, 16, 11), tg1(16, 16, 1);
        transpose_conv<<<tgK, 256, 0, stream>>>(tW1, wt + 0L * WM);
        transpose_conv<<<tgK, 256, 0, stream>>>(tW2, wt + 11L * WM);
        conv_f32_bf16<<<(unsigned)((11 * WM / 4 + 255) / 256), 256, 0, stream>>>(
            tW3, wt + 22L * WM, 11 * WM);
        transpose_conv<<<tg1, 256, 0, stream>>>(eW1, wt + 33L * WM);
        transpose_conv<<<tg1, 256, 0, stream>>>(eW2, wt + 34L * WM);
        transpose_conv<<<tg1, 256, 0, stream>>>(eW3, wt + 35L * WM);

        hipMemsetAsync(zero512, 0, 512 * sizeof(float), stream);
        gemm_bt<false><<<dim3(4, 1, 11), 512, 0, stream>>>(
            wt + 33L * WM, 0, wt + 22L * WM, WM, zero512, 0, Mt + WM, WM);
        hipMemcpyAsync(Mt, wt + 33L * WM, WM * sizeof(short),
                       hipMemcpyDeviceToDevice, stream);
        hipMemcpyAsync(bB, eb1, 512 * sizeof(float),
                       hipMemcpyDeviceToDevice, stream);
        bias_fold<<<(11 * 512) / 4, 256, 0, stream>>>(tb3, wt + 33L * WM, eb1, bB);
    }

    const long SC = CH * 512;
    const dim3 gM((unsigned)(CH / 64), 1, 12);

    for (int ch = 0; ch < c; ++ch) {
        conv_f32_bf16<<<(unsigned)((SC / 4 + 255) / 256), 256, 0, stream>>>(
            x + (long)ch * SC, xb, SC);

        mega<<<gM, 512, 0, stream>>>(xb, wt, Mt, tb1, tb2, bB, eb2, eb3, T, (int)CH);

        ln_loss<<<(unsigned)(CH / 4), 256, 0, stream>>>(
            T, ln_g, ln_b, (float*)d_out + (long)ch * CH, (int)CH);
    }
}

// Round 22
// 961.112 us; speedup vs baseline: 1.4638x; 1.4638x over previous
//
#include <hip/hip_runtime.h>
#include <hip/hip_bf16.h>
#include <cstdint>

typedef __attribute__((ext_vector_type(8))) short short8;
typedef __attribute__((ext_vector_type(4))) float f32x4;
typedef __attribute__((ext_vector_type(4))) short short4v;

__device__ __forceinline__ float b2f(short s) {
    unsigned u = ((unsigned)(unsigned short)s) << 16;
    return __builtin_bit_cast(float, u);
}
__device__ __forceinline__ short f2b(float f) {
    unsigned u = __builtin_bit_cast(unsigned, f);
    u += 0x7fff + ((u >> 16) & 1);   // RNE
    return (short)(u >> 16);
}

// tanh-form GELU, 8-VALU: gelu = x - x/(1+exp2(x*(c1 + c2*x^2)))
__device__ __forceinline__ float gelu_t(float x) {
    const float c1 = 2.302184829f;     // 2*log2(e)*0.7978845608
    const float c2 = 0.102947246f;     // c1 * 0.044715
    float x2 = x * x;
    float t  = __builtin_fmaf(c2, x2, c1);
    float e  = __builtin_amdgcn_exp2f(x * t);
    return x - __fdividef(x, e + 1.0f);
}

__device__ __forceinline__ void async16(const void* g, void* l) {
    __builtin_amdgcn_global_load_lds(
        (const __attribute__((address_space(1))) unsigned int*)g,
        (__attribute__((address_space(3))) unsigned int*)l, 16, 0, 0);
}

#define VMW(N) asm volatile("s_waitcnt vmcnt(" #N ")" ::: "memory")

// =====================================================================
// 256x256-tile GEMM, K=512, 8-phase counted-vmcnt schedule (r20-best):
//  - even-phase waits (vmcnt(8); tail 8,8,4,0), one raw barrier/phase
//  - B-fragment register reuse across the (mh=0,1) phase pair
// =====================================================================
template<bool GELU>
__global__ __launch_bounds__(512)
void gemm_bt(const short* __restrict__ A, long sA,
             const short* __restrict__ Bt, long sB,
             const float* __restrict__ bias, long sBias,
             short* __restrict__ C, long sC) {
    const int z = blockIdx.z;
    A    += (long)z * sA;
    Bt   += (long)z * sB;
    bias += (long)z * sBias;
    C    += (long)z * sC;

    const int nwg = (int)gridDim.x;
    const int bx  = (int)blockIdx.x;
    int flat = bx;
    if ((nwg & 7) == 0) { const int q = nwg >> 3; flat = (bx & 7) * q + (bx >> 3); }
    const long arow0 = (long)(flat >> 1) * 256;
    const long brow0 = (long)(flat & 1) * 256;

    // 2 bufs x [A_k0|A_k1|B_k0|B_k1] x 8192 shorts = 128 KB
    __shared__ alignas(16) short smem[2 * 32768];

    const int tid  = threadIdx.x;
    const int lane = tid & 63;
    const int w    = tid >> 6;             // 0..7
    const int wrow = w >> 2, wcol = w & 3; // 2M x 4N wave grid
    const int lr = lane & 15, hi = lane >> 4;

    f32x4 acc[8][4] = {};

    // stage one half-tile [256 rows][32 k]; rows 64 B; key (row>>1)&3
    auto stageH = [&](int st, int sks, int sB_) {
        short* reg = smem + (st & 1) * 32768 + (sB_ ? 16384 : 0) + sks * 8192;
        const short* srcb = sB_ ? Bt : A;
        const long r0g = sB_ ? brow0 : arow0;
        const int kc = st * 64 + sks * 32;
#pragma unroll
        for (int jj = 0; jj < 2; ++jj) {
            const int R = w * 32 + jj * 16;
            const int row = R + (lane >> 2);
            const int gc = (lane & 3) ^ ((row >> 1) & 3);
            async16(srcb + (r0g + row) * 512 + kc + gc * 8, reg + R * 32);
        }
    };

    // ---- prologue: t0 all 4 halves + t1 k0 (12 loads) ----
    stageH(0, 0, 0); stageH(0, 0, 1);
    stageH(0, 1, 0); stageH(0, 1, 1);
    stageH(1, 0, 0); stageH(1, 0, 1);

    short8 b[4];   // lives across the (mh=0,1) phase pair

#pragma unroll
    for (int i = 0; i < 4; ++i) {
#pragma unroll
        for (int p = 0; p < 8; ++p) {
            const int tau = 2 * i + (p >> 2);
            const int ks  = (p >> 1) & 1;
            const int mh  = p & 1;
            const short* Ar = smem + (tau & 1) * 32768 + ks * 8192;
            const short* Br = Ar + 16384;

            if (mh == 0) {
                // even phase: wait for half (tau,ks), publish, then read
                if (i < 3)       { VMW(8); }
                else if (p == 0) { VMW(8); }
                else if (p == 2) { VMW(8); }
                else if (p == 4) { VMW(4); }
                else             { VMW(0); }
                __builtin_amdgcn_s_barrier();
                __builtin_amdgcn_sched_barrier(0);
                // B fragments: once per pair (register reuse at mh==1)
#pragma unroll
                for (int n = 0; n < 4; ++n) {
                    const int row = wcol * 64 + n * 16 + lr;
                    b[n] = *(const short8*)&Br[row * 32 + ((hi ^ ((row >> 1) & 3)) << 3)];
                }
            }

            short8 a[4];
#pragma unroll
            for (int j = 0; j < 4; ++j) {
                const int row = wrow * 128 + (mh * 4 + j) * 16 + lr;
                a[j] = *(const short8*)&Ar[row * 32 + ((hi ^ ((row >> 1) & 3)) << 3)];
            }

            // stage schedule (r18-verified stagger)
            {
                const int st  = (p < 2) ? 2 * i + 1 : (p < 6) ? 2 * i + 2 : 2 * i + 3;
                const int sks = (p < 2) ? 1 : (p < 4) ? 0 : (p < 6) ? 1 : 0;
                const int sB_ = p & 1;
                if (st < 8) stageH(st, sks, sB_);
            }

            __builtin_amdgcn_s_setprio(1);
#pragma unroll
            for (int j = 0; j < 4; ++j)
#pragma unroll
                for (int n = 0; n < 4; ++n)
                    acc[mh * 4 + j][n] = __builtin_amdgcn_mfma_f32_16x16x32_bf16(
                        a[j], b[n], acc[mh * 4 + j][n], 0, 0, 0);
            __builtin_amdgcn_s_setprio(0);

            if (mh == 1) {
                // odd phase: trailing barrier gates next phases' staging
                __builtin_amdgcn_sched_barrier(0);
                __builtin_amdgcn_s_barrier();
            }
        }
    }

    // ---- epilogue: 4 half-passes of 32 rows; wave-private E = [32][72] ----
    short* E = smem + w * (32 * 72);
    const int cl = lr, rl = hi * 4;
#pragma unroll
    for (int h = 0; h < 4; ++h) {
#pragma unroll
        for (int n = 0; n < 4; ++n) {
            const int col = (int)brow0 + wcol * 64 + n * 16 + cl;
            const float bs = bias[col];
            const int ecol = n * 16 + cl;
#pragma unroll
            for (int ml = 0; ml < 2; ++ml) {
                const int m = h * 2 + ml;
                float g0 = acc[m][n][0] + bs, g1 = acc[m][n][1] + bs;
                float g2 = acc[m][n][2] + bs, g3 = acc[m][n][3] + bs;
                if (GELU) { g0 = gelu_t(g0); g1 = gelu_t(g1); g2 = gelu_t(g2); g3 = gelu_t(g3); }
                unsigned p01, p23;
                asm("v_cvt_pk_bf16_f32 %0, %1, %2" : "=v"(p01) : "v"(g0), "v"(g1));
                asm("v_cvt_pk_bf16_f32 %0, %1, %2" : "=v"(p23) : "v"(g2), "v"(g3));
                const int r0 = ml * 16 + rl;
                E[(r0 + 0) * 72 + ecol] = (short)(p01 & 0xffff);
                E[(r0 + 1) * 72 + ecol] = (short)(p01 >> 16);
                E[(r0 + 2) * 72 + ecol] = (short)(p23 & 0xffff);
                E[(r0 + 3) * 72 + ecol] = (short)(p23 >> 16);
            }
        }
        // wave-private region: LDS ops in-order within a wave
#pragma unroll
        for (int chunk = 0; chunk < 4; ++chunk) {
            const int rloc = chunk * 8 + (lane >> 3);
            const int c0   = (lane & 7) * 8;
            short8 v = *(const short8*)&E[rloc * 72 + c0];
            *(short8*)&C[(arow0 + wrow * 128 + h * 32 + rloc) * 512
                         + brow0 + wcol * 64 + c0] = v;
        }
    }
}

// ---- transpose+convert: dst[n][k] = bf16(src[k][n]), one 512x512 per blockIdx.z ----
__global__ __launch_bounds__(256)
void transpose_conv(const float* __restrict__ src, short* __restrict__ dst) {
    __shared__ float t[32][33];
    const long moff = (long)blockIdx.z * 512 * 512;
    const float* s = src + moff;
    short* d = dst + moff;
    const int tx = threadIdx.x & 31, ty = threadIdx.x >> 5;
    const int bi = blockIdx.x, bj = blockIdx.y;
#pragma unroll
    for (int j = 0; j < 4; ++j)
        t[ty + j * 8][tx] = s[(long)(bi * 32 + ty + j * 8) * 512 + bj * 32 + tx];
    __syncthreads();
#pragma unroll
    for (int j = 0; j < 4; ++j)
        d[(long)(bj * 32 + ty + j * 8) * 512 + bi * 32 + tx] = f2b(t[tx][ty + j * 8]);
}

// ---- f32 -> bf16 elementwise ----
__global__ __launch_bounds__(256)
void conv_f32_bf16(const float* __restrict__ src, short* __restrict__ dst, long n) {
    long i = ((long)blockIdx.x * 256 + threadIdx.x) * 4;
    if (i >= n) return;
    float4 f = *(const float4*)&src[i];
    short4v o;
    o[0] = f2b(f.x); o[1] = f2b(f.y); o[2] = f2b(f.z); o[3] = f2b(f.w);
    *(short4v*)&dst[i] = o;
}

// ---- bias fold: bB[(k+1)*512+n] = dot(tb3_k, eW1[:,n]) + eb1[n] ----
__global__ __launch_bounds__(256)
void bias_fold(const float* __restrict__ tb3, const short* __restrict__ wtE1,
               const float* __restrict__ eb1, float* __restrict__ bB) {
    const int wid = threadIdx.x >> 6, lane = threadIdx.x & 63;
    const int idx = blockIdx.x * 4 + wid;        // 0 .. 11*512-1
    const int k = idx >> 9, n = idx & 511;
    short8 wv = *(const short8*)&wtE1[(long)n * 512 + lane * 8];
    const float* tb = tb3 + (long)k * 512 + lane * 8;
    float s = 0.f;
#pragma unroll
    for (int j = 0; j < 8; ++j) s += b2f(wv[j]) * tb[j];
#pragma unroll
    for (int o = 1; o < 64; o <<= 1) s += __shfl_xor(s, o, 64);
    if (lane == 0) bB[(long)(k + 1) * 512 + n] = s + eb1[n];
}

// ---- fused LN + L2-normalize + MFMA Gram + logsumexp loss (r12-proven) ----
__global__ __launch_bounds__(256)
void ln_loss(const short* __restrict__ H, const float* __restrict__ g,
             const float* __restrict__ bta, float* __restrict__ out, int CH) {
    __shared__ alignas(16) short Z[4][16 * 520];
    const int wid = threadIdx.x >> 6, lane = threadIdx.x & 63;
    const long b = (long)blockIdx.x * 4 + wid;
    short* Zw = &Z[wid][0];

#pragma unroll
    for (int r = 12; r < 16; ++r)
        *(short8*)&Zw[r * 520 + lane * 8] = (short8){0, 0, 0, 0, 0, 0, 0, 0};

    for (int s = 0; s < 12; ++s) {
        short8 t = *(const short8*)&H[((long)s * CH + b) * 512 + lane * 8];
        float v[8];
        float sum = 0.f, ss = 0.f;
#pragma unroll
        for (int j = 0; j < 8; ++j) { v[j] = b2f(t[j]); sum += v[j]; ss += v[j] * v[j]; }
#pragma unroll
        for (int o = 1; o < 64; o <<= 1) { sum += __shfl_xor(sum, o, 64); ss += __shfl_xor(ss, o, 64); }
        const float mu = sum * (1.f / 512.f);
        const float rs = rsqrtf(ss * (1.f / 512.f) - mu * mu + 1e-5f);
        float y[8]; float nsq = 0.f;
#pragma unroll
        for (int j = 0; j < 8; ++j) {
            const int col = lane * 8 + j;
            y[j] = (v[j] - mu) * rs * g[col] + bta[col];
            nsq += y[j] * y[j];
        }
#pragma unroll
        for (int o = 1; o < 64; o <<= 1) nsq += __shfl_xor(nsq, o, 64);
        const float inv = 1.f / fmaxf(sqrtf(nsq), 1e-8f);
        short8 o8;
#pragma unroll
        for (int j = 0; j < 8; ++j) o8[j] = f2b(y[j] * inv);
        *(short8*)&Zw[s * 520 + lane * 8] = o8;
    }

    f32x4 acc = {0.f, 0.f, 0.f, 0.f};
    const int lr = lane & 15, hi = lane >> 4;
#pragma unroll
    for (int st = 0; st < 16; ++st) {
        short8 a = *(const short8*)&Zw[lr * 520 + st * 32 + hi * 8];
        acc = __builtin_amdgcn_mfma_f32_16x16x32_bf16(a, a, acc, 0, 0, 0);
    }
    const int col = lr;
    float lmax = -3.0e38f;
    bool valid[4];
#pragma unroll
    for (int i = 0; i < 4; ++i) {
        const int row = hi * 4 + i;
        valid[i] = (row < 12) && (row != col);
        if (valid[i]) lmax = fmaxf(lmax, acc[i]);
    }
    lmax = fmaxf(lmax, __shfl_xor(lmax, 16, 64));
    lmax = fmaxf(lmax, __shfl_xor(lmax, 32, 64));
    float esum = 0.f;
#pragma unroll
    for (int i = 0; i < 4; ++i)
        if (valid[i]) esum += __builtin_amdgcn_exp2f((acc[i] - lmax) * 1.44269504f);
    esum += __shfl_xor(esum, 16, 64);
    esum += __shfl_xor(esum, 32, 64);
    float contrib = 0.f;
    if (hi == 0 && col >= 1 && col <= 11) {
        const float logden = lmax + __builtin_amdgcn_logf(esum) * 0.6931471806f;
        contrib = acc[0] - logden;
    }
#pragma unroll
    for (int o = 1; o < 16; o <<= 1) contrib += __shfl_xor(contrib, o, 64);
    if (lane == 0) out[b] = -contrib;
}

// ---------------- host ----------------
extern "C" void kernel_launch(void* const* d_in, const int* in_sizes, int n_in,
                              void* d_out, int out_size, void* d_ws, size_t ws_size,
                              hipStream_t stream) {
    const float* x    = (const float*)d_in[0];
    const float* tW1  = (const float*)d_in[1];
    const float* tb1  = (const float*)d_in[2];
    const float* tW2  = (const float*)d_in[3];
    const float* tb2  = (const float*)d_in[4];
    const float* tW3  = (const float*)d_in[5];
    const float* tb3  = (const float*)d_in[6];
    const float* eW1  = (const float*)d_in[7];
    const float* eb1  = (const float*)d_in[8];
    const float* eW2  = (const float*)d_in[9];
    const float* eb2  = (const float*)d_in[10];
    const float* eW3  = (const float*)d_in[11];
    const float* eb3  = (const float*)d_in[12];
    const float* ln_g = (const float*)d_in[13];
    const float* ln_b = (const float*)d_in[14];

    const int  B    = in_sizes[0] / 512;   // 16384
    const long WMAT = 512L * 512L;

    int  c  = 1;
    long CH = B;
    for (;;) {
        CH = (long)B / c;
        size_t need = (size_t)48 * WMAT * 2 + (512 + 12 * 512) * 4
                    + (size_t)24 * CH * 512 * 2 + 8192;
        if (need <= ws_size || CH <= 256) break;
        c <<= 1;
    }
    const long SLAB = 12L * CH * 512;

    short* wt   = (short*)d_ws;             // 0..21: tW1^T,tW2^T; 22..32: tW3 (orig); 33..35: eW^T
    short* Mt   = wt + 36L * WMAT;          // slot0 = eW1^T, 1..11 = (tW3_k·eW1)^T
    float* zero512 = (float*)(Mt + 12L * WMAT);
    float* bB   = zero512 + 512;            // 12x512 folded biases
    short* S    = (short*)(bB + 12 * 512);  // slab S [12, CH, 512]
    short* T    = S + SLAB;                 // slab T [12, CH, 512]

    // --- weight prep (once per launch) ---
    {
        dim3 tgK(16, 16, 11), tg1(16, 16, 1);
        transpose_conv<<<tgK, 256, 0, stream>>>(tW1, wt + 0L * WMAT);
        transpose_conv<<<tgK, 256, 0, stream>>>(tW2, wt + 11L * WMAT);
        conv_f32_bf16<<<(unsigned)((11 * WMAT / 4 + 255) / 256), 256, 0, stream>>>(
            tW3, wt + 22L * WMAT, 11 * WMAT);
        transpose_conv<<<tg1, 256, 0, stream>>>(eW1, wt + 33L * WMAT);
        transpose_conv<<<tg1, 256, 0, stream>>>(eW2, wt + 34L * WMAT);
        transpose_conv<<<tg1, 256, 0, stream>>>(eW3, wt + 35L * WMAT);

        hipMemsetAsync(zero512, 0, 512 * sizeof(float), stream);
        gemm_bt<false><<<dim3(4, 1, 11), 512, 0, stream>>>(
            wt + 33L * WMAT, 0, wt + 22L * WMAT, WMAT, zero512, 0, Mt + WMAT, WMAT);
        hipMemcpyAsync(Mt, wt + 33L * WMAT, WMAT * sizeof(short),
                       hipMemcpyDeviceToDevice, stream);
        hipMemcpyAsync(bB, eb1, 512 * sizeof(float),
                       hipMemcpyDeviceToDevice, stream);
        bias_fold<<<(11 * 512) / 4, 256, 0, stream>>>(tb3, wt + 33L * WMAT, eb1, bB);
    }

    const long SC = CH * 512;
    const dim3 gT((unsigned)(CH / 256 * 2), 1, 11);       // L1,L2: M = CH
    const dim3 gF((unsigned)(CH / 256 * 2), 1, 12);       // fold pass: 12 views
    const dim3 gE((unsigned)(12 * CH / 256 * 2), 1, 1);   // E2,E3: M = 12*CH

    for (int ch = 0; ch < c; ++ch) {
        conv_f32_bf16<<<(unsigned)((SC / 4 + 255) / 256), 256, 0, stream>>>(
            x + (long)ch * SC, S, SC);

        gemm_bt<true ><<<gT, 512, 0, stream>>>(S, 0,  wt + 0L * WMAT,  WMAT, tb1, 512, T + SC, SC);
        gemm_bt<true ><<<gT, 512, 0, stream>>>(T + SC, SC, wt + 11L * WMAT, WMAT, tb2, 512, S + SC, SC);
        gemm_bt<true ><<<gF, 512, 0, stream>>>(S, SC, Mt, WMAT, bB, 512, T, SC);
        gemm_bt<true ><<<gE, 512, 0, stream>>>(T, 0, wt + 34L * WMAT, 0, eb2, 0, S, 0);
        gemm_bt<false><<<gE, 512, 0, stream>>>(S, 0, wt + 35L * WMAT, 0, eb3, 0, T, 0);

        ln_loss<<<(unsigned)(CH / 4), 256, 0, stream>>>(
            T, ln_g, ln_b, (float*)d_out + (long)ch * CH, (int)CH);
    }
}